// Round 3
// baseline (3296.161 us; speedup 1.0000x reference)
//
#include <hip/hip_runtime.h>

// 2-layer GCN, CSR-gather, bf16 payloads, zero global atomics.
//   hist(512-node buckets) -> scan1/scan2 -> [scatter ∥ gemm, 1:1] -> sort
//   -> gather1 -> gather2f (gather + W2 matmul + pooled output, fused).
// Kept: 1:1 scatter/gemm interleave (R9), 512-node buckets, packed 1-int
// bucket entries, bf16 h1 (R10), scan3g folded into consumers (R10),
// final fused into gather2 (R10), sorted coalesced bucket writes (R12),
// scan-diff counts + shfl scan + LDS union (R13), uint4 gathers (R13).
// R14: gemm role x-loads restructured.  Was: thread-per-row direct loads ->
//      every wave vmem instr touched 64 distinct cache lines (512B lane
//      stride); transaction-rate/latency bound at 15% VALU, 93us vs ~25us
//      traffic floor.  Now: per 16-float K-chunk, cooperative coalesced
//      load (4 lanes = one full 64B line, 16 lines/instr), transposed
//      store xs[kk][row] (2-way banks, free), conflict-free stride-1 LDS
//      reads, next chunk global-loaded to regs BEFORE the barrier so HBM
//      latency hides under the 256-FMA burst (T14 async-split).

#define TPB 256
#define CHUNK 4096          // edges per stage-1 block (1:1 with gemm blocks)
#define BK_SHIFT 9
#define NPB 512             // nodes per bucket = 1 << BK_SHIFT
#define XSL 260             // xs row stride in floats (bank-spread pad)

__device__ __forceinline__ float bf2f(unsigned short u) {
    union { unsigned int i; float f; } v; v.i = ((unsigned int)u) << 16; return v.f;
}
__device__ __forceinline__ unsigned short f2bf(float f) {
    union { float f; unsigned int i; } v; v.f = f;
    unsigned int r = v.i + 0x7fff + ((v.i >> 16) & 1);   // RNE
    return (unsigned short)(r >> 16);
}
// accumulate 8 bf16 (one uint4) into a[0..7]; mask kills invalid edges
__device__ __forceinline__ void bfacc8(uint4 v, unsigned int m, float* a) {
    union { unsigned int i; float f; } lo, hi;
    v.x &= m; v.y &= m; v.z &= m; v.w &= m;
    lo.i = v.x << 16; hi.i = v.x & 0xffff0000u; a[0] += lo.f; a[1] += hi.f;
    lo.i = v.y << 16; hi.i = v.y & 0xffff0000u; a[2] += lo.f; a[3] += hi.f;
    lo.i = v.z << 16; hi.i = v.z & 0xffff0000u; a[4] += lo.f; a[5] += hi.f;
    lo.i = v.w << 16; hi.i = v.w & 0xffff0000u; a[6] += lo.f; a[7] += hi.f;
}
__device__ __forceinline__ void bfunp8(uint4 v, float* a) {
    union { unsigned int i; float f; } lo, hi;
    lo.i = v.x << 16; hi.i = v.x & 0xffff0000u; a[0] = lo.f; a[1] = hi.f;
    lo.i = v.y << 16; hi.i = v.y & 0xffff0000u; a[2] = lo.f; a[3] = hi.f;
    lo.i = v.z << 16; hi.i = v.z & 0xffff0000u; a[4] = lo.f; a[5] = hi.f;
    lo.i = v.w << 16; hi.i = v.w & 0xffff0000u; a[6] = lo.f; a[7] = hi.f;
}

// S1a: counts[bk*nblk + blk] = #edges in block blk with col>>9 == bk
__global__ __launch_bounds__(TPB) void hist_kernel(const int* __restrict__ col,
                                                   int* __restrict__ counts,
                                                   int E, int nblk, int nbuck) {
    __shared__ int hist[512];
    int t = threadIdx.x;
    for (int i = t; i < nbuck; i += TPB) hist[i] = 0;
    __syncthreads();
    int e0 = blockIdx.x * CHUNK;
    for (int i = t; i < CHUNK; i += TPB) {
        int e = e0 + i;
        if (e < E) atomicAdd(&hist[col[e] >> BK_SHIFT], 1);   // LDS atomic
    }
    __syncthreads();
    for (int i = t; i < nbuck; i += TPB) counts[i * nblk + blockIdx.x] = hist[i];
}

// scan1: per-256-block exclusive scan (counts in place), bsum[b]=block total
__global__ __launch_bounds__(TPB) void scan1_kernel(const int* __restrict__ in,
                                                    int* __restrict__ out,
                                                    int* __restrict__ bsum, int L) {
    __shared__ int s[TPB];
    int t = threadIdx.x;
    int i = blockIdx.x * TPB + t;
    int d = (i < L) ? in[i] : 0;
    s[t] = d; __syncthreads();
    for (int off = 1; off < TPB; off <<= 1) {
        int v = (t >= off) ? s[t - off] : 0;
        __syncthreads();
        s[t] += v;
        __syncthreads();
    }
    if (i < L) out[i] = s[t] - d;
    if (t == TPB - 1) bsum[blockIdx.x] = s[t];
}

// scan2: single-block exclusive scan of up to 2048 block sums (2 elems/thread)
__global__ __launch_bounds__(1024) void scan2_kernel(int* __restrict__ bsum, int nb) {
    __shared__ int s[1024];
    int t = threadIdx.x;
    int i0 = t * 2, i1 = t * 2 + 1;
    int v0 = (i0 < nb) ? bsum[i0] : 0;
    int v1 = (i1 < nb) ? bsum[i1] : 0;
    int pv = v0 + v1;
    s[t] = pv; __syncthreads();
    for (int off = 1; off < 1024; off <<= 1) {
        int u = (t >= off) ? s[t - off] : 0;
        __syncthreads();
        s[t] += u;
        __syncthreads();
    }
    int exc = s[t] - pv;
    if (i0 < nb) bsum[i0] = exc;
    if (i1 < nb) bsum[i1] = exc + v0;
}

// cbase[f] = counts[f] + bsum[f>>8]   (scan3g folded into consumers)
__device__ __forceinline__ int cbase_at(const int* counts, const int* bsum, int f) {
    return counts[f] + bsum[f >> 8];
}

// one 16-col window of the x@W1 microkernel
#define GEMM_W16(XV, GB)                                                          \
    {                                                                             \
        _Pragma("unroll")                                                         \
        for (int cc = 0; cc < 16; ++cc) {                                         \
            const float4* w4 = (const float4*)&w1s[((GB) * 16 + cc) * 16];        \
            float4 wa = w4[0], wb = w4[1], wc = w4[2], wd = w4[3];                \
            float xc = (XV)[cc];                                                  \
            acc[0]  = fmaf(xc, wa.x, acc[0]);  acc[1]  = fmaf(xc, wa.y, acc[1]);  \
            acc[2]  = fmaf(xc, wa.z, acc[2]);  acc[3]  = fmaf(xc, wa.w, acc[3]);  \
            acc[4]  = fmaf(xc, wb.x, acc[4]);  acc[5]  = fmaf(xc, wb.y, acc[5]);  \
            acc[6]  = fmaf(xc, wb.z, acc[6]);  acc[7]  = fmaf(xc, wb.w, acc[7]);  \
            acc[8]  = fmaf(xc, wc.x, acc[8]);  acc[9]  = fmaf(xc, wc.y, acc[9]);  \
            acc[10] = fmaf(xc, wc.z, acc[10]); acc[11] = fmaf(xc, wc.w, acc[11]); \
            acc[12] = fmaf(xc, wd.x, acc[12]); acc[13] = fmaf(xc, wd.y, acc[13]); \
            acc[14] = fmaf(xc, wd.z, acc[14]); acc[15] = fmaf(xc, wd.w, acc[15]); \
        }                                                                         \
    }

// cooperative coalesced load of K-chunk c into 4 float4 regs
#define LOADC(DST, C)                                                             \
    {                                                                             \
        _Pragma("unroll")                                                         \
        for (int it = 0; it < 4; ++it) {                                          \
            int idx = it * 256 + t;                                               \
            int r = idx >> 2, j = idx & 3;                                        \
            size_t gr = (size_t)min(n0g + r, N - 1);                              \
            DST[it] = xg4[gr * 32 + (size_t)((C) * 4 + j)];                       \
        }                                                                         \
    }
// transposed store: xs[kk][row], kk = j*4+q  (2 lanes/bank per instr = free)
#define STOREC(SRC)                                                               \
    {                                                                             \
        _Pragma("unroll")                                                         \
        for (int it = 0; it < 4; ++it) {                                          \
            int idx = it * 256 + t;                                               \
            int r = idx >> 2, j = idx & 3;                                        \
            float4 v = SRC[it];                                                   \
            xs[(j * 4 + 0) * XSL + r] = v.x;                                      \
            xs[(j * 4 + 1) * XSL + r] = v.y;                                      \
            xs[(j * 4 + 2) * XSL + r] = v.z;                                      \
            xs[(j * 4 + 3) * XSL + r] = v.w;                                      \
        }                                                                         \
    }

// S1c ∥ gemm, block-interleaved 1:1.
// Scatter: counts from scan diffs, shfl-scan local offsets, LDS counting
//   sort, bucket-ordered coalesced writes.
// Gemm: coalesced LDS-staged x chunks (see R14 header note).
__global__ __launch_bounds__(TPB) void s1c_gemm_kernel(
        const int* __restrict__ row, const int* __restrict__ col,
        const int* __restrict__ counts, const int* __restrict__ bsum,
        int E, int nblk, int nbuck,
        int* __restrict__ bucketed,
        const float* __restrict__ x, const float* __restrict__ W1,
        unsigned short* __restrict__ h1b, int N, int nbg) {
    // unioned LDS: scatter uses 12352 B, gemm uses 8192 + 16640 B
    __shared__ __align__(16) char sbuf[8192 + 16 * XSL * 4];
    int* slhist = (int*)sbuf;                               // 512 ints (cursor)
    int* sgd    = (int*)(sbuf + 2048);                      // 512 ints
    unsigned short* ssidx = (unsigned short*)(sbuf + 4096); // 4096 ushort
    int* swtot  = (int*)(sbuf + 4096 + 8192);               // 4 ints
    float* w1s  = (float*)sbuf;                             // gemm: 8 KB
    float* xs   = (float*)(sbuf + 8192);                    // gemm: 16x260 f32

    int b = (int)blockIdx.x, t = threadIdx.x;
    int M = min(nblk, nbg);
    int role, id;
    if (b < 2 * M) { role = b & 1; id = b >> 1; }
    else           { role = (nblk > nbg) ? 0 : 1; id = b - M; }

    if (role == 0) {                         // block-local counting sort
        int e0 = id * CHUNK;
        int nE = min(CHUNK, E - e0);
        int Ltot = nbuck * nblk;
        int lane = t & 63, w = t >> 6;
        int bk0 = 2 * t, bk1 = 2 * t + 1;
        // per-bin counts for this chunk from global-scan differences
        int cb0 = 0, cb1 = 0, c0 = 0, c1 = 0;
        if (bk0 < nbuck) {
            int f = bk0 * nblk + id;
            cb0 = cbase_at(counts, bsum, f);
            int nx = (f + 1 < Ltot) ? cbase_at(counts, bsum, f + 1) : E;
            c0 = nx - cb0;
        }
        if (bk1 < nbuck) {
            int f = bk1 * nblk + id;
            cb1 = cbase_at(counts, bsum, f);
            int nx = (f + 1 < Ltot) ? cbase_at(counts, bsum, f + 1) : E;
            c1 = nx - cb1;
        }
        int s = c0 + c1;
        // wave inclusive scan of s over 64 lanes (bin order == thread order)
        int v = s;
#pragma unroll
        for (int d = 1; d < 64; d <<= 1) {
            int u2 = __shfl_up(v, d, 64);
            if (lane >= d) v += u2;
        }
        if (lane == 63) swtot[w] = v;
        __syncthreads();
        int wbase = 0;
#pragma unroll
        for (int i = 0; i < 4; ++i) wbase += (i < w) ? swtot[i] : 0;
        int o0 = wbase + v - s;              // local exclusive start of bk0
        int o1 = o0 + c0;
        if (bk0 < nbuck) { slhist[bk0] = o0; sgd[bk0] = cb0 - o0; }
        if (bk1 < nbuck) { slhist[bk1] = o1; sgd[bk1] = cb1 - o1; }
        __syncthreads();
        // scatter chunk-local indices into sorted order
        for (int i = t; i < nE; i += TPB) {
            int c = col[e0 + i];
            int lp = atomicAdd(&slhist[c >> BK_SHIFT], 1);     // LDS atomic
            ssidx[lp] = (unsigned short)i;
        }
        __syncthreads();
        // write out in bucket order -> runs of consecutive addresses
        for (int j = t; j < nE; j += TPB) {
            int i = ssidx[j];
            int c = col[e0 + i];                               // L1/L2-hot
            int r = row[e0 + i];
            bucketed[sgd[c >> BK_SHIFT] + j] = ((c & (NPB - 1)) << 18) | r;
        }
        return;
    }
    // gemm: h1b[n] = bf16(x[n] @ W1), LDS-staged coalesced x, W1 in LDS
    for (int i = t; i < 128 * 16; i += TPB) w1s[i] = W1[i];
    int n0g = id * TPB;
    int n = n0g + t;
    const float4* xg4 = (const float4*)x;
    float acc[16];
#pragma unroll
    for (int k = 0; k < 16; ++k) acc[k] = 0.f;
    float4 st[4];
    LOADC(st, 0);
    STOREC(st);
#pragma unroll
    for (int c = 0; c < 8; ++c) {
        float4 nx[4];
        if (c < 7) LOADC(nx, c + 1);         // issue before barrier: latency
        __syncthreads();                     //   hides under this chunk's FMAs
        float xv[16];
#pragma unroll
        for (int kk = 0; kk < 16; ++kk) xv[kk] = xs[kk * XSL + t];
        GEMM_W16(xv, c);
        __syncthreads();                     // reads done before overwrite
        if (c < 7) STOREC(nx);
    }
    if (n < N) {
        unsigned int u[8];
#pragma unroll
        for (int j = 0; j < 8; ++j)
            u[j] = (unsigned int)f2bf(acc[2 * j]) | ((unsigned int)f2bf(acc[2 * j + 1]) << 16);
        uint4* o = (uint4*)(h1b + (size_t)n * 16);
        o[0] = make_uint4(u[0], u[1], u[2], u[3]);
        o[1] = make_uint4(u[4], u[5], u[6], u[7]);
    }
}

// S2: one block per 512-node bucket: counting sort, emit csr/offs/dinv,
// h1p = bf16(dinv * h1b).
__global__ __launch_bounds__(TPB) void sort_kernel(
        const int* __restrict__ bucketed,
        const int* __restrict__ counts, const int* __restrict__ bsum,
        int E, int nblk, int nbuck,
        int* __restrict__ csr, int* __restrict__ offs, float* __restrict__ dinv,
        const unsigned short* __restrict__ h1b, unsigned short* __restrict__ h1p, int N) {
    __shared__ int lhist[NPB];
    __shared__ int part[TPB];
    __shared__ float sdinv[NPB];
    int bk = blockIdx.x, t = threadIdx.x;
    int n0 = bk << BK_SHIFT;
    int n1 = min(n0 + NPB, N);
    int e0 = cbase_at(counts, bsum, bk * nblk);
    int e1 = (bk + 1 < nbuck) ? cbase_at(counts, bsum, (bk + 1) * nblk) : E;

    lhist[t] = 0; lhist[t + TPB] = 0;
    __syncthreads();
    for (int i = e0 + t; i < e1; i += TPB)
        atomicAdd(&lhist[bucketed[i] >> 18], 1);               // LDS atomic
    __syncthreads();

    int base = t * 2;
    int c0 = lhist[base], c1 = lhist[base + 1];
    int s = c0 + c1;
    part[t] = s;
    __syncthreads();
    for (int off = 1; off < TPB; off <<= 1) {
        int v = (t >= off) ? part[t - off] : 0;
        __syncthreads();
        part[t] += v;
        __syncthreads();
    }
    int o0 = e0 + part[t] - s;
    int o1 = o0 + c0;
    lhist[base] = o0; lhist[base + 1] = o1;
    sdinv[base]     = rsqrtf((float)c0 + 1.0f);
    sdinv[base + 1] = rsqrtf((float)c1 + 1.0f);
    int n = n0 + base;
    if (n + 0 < N) { offs[n + 0] = o0; dinv[n + 0] = sdinv[base]; }
    if (n + 1 < N) { offs[n + 1] = o1; dinv[n + 1] = sdinv[base + 1]; }
    __syncthreads();

    for (int i = e0 + t; i < e1; i += TPB) {
        int v = bucketed[i];
        int pos = atomicAdd(&lhist[v >> 18], 1);               // LDS atomic
        csr[pos] = v & 0x3FFFF;
    }
    int nq = (n1 - n0) * 4;                  // one quad (4 feats) per i
    for (int i = t; i < nq; i += TPB) {
        float dv = sdinv[i >> 2];
        uint2 u = ((const uint2*)h1b)[(size_t)n0 * 4 + i];
        float f0 = bf2f((unsigned short)(u.x & 0xffff));
        float f1 = bf2f((unsigned short)(u.x >> 16));
        float f2 = bf2f((unsigned short)(u.y & 0xffff));
        float f3 = bf2f((unsigned short)(u.y >> 16));
        ((ushort4*)h1p)[(size_t)n0 * 4 + i] =
            make_ushort4(f2bf(f0 * dv), f2bf(f1 * dv), f2bf(f2 * dv), f2bf(f3 * dv));
    }
    if (bk == 0 && t == 0) offs[N] = E;
}

// gather1: 16 lanes/node, uint4 gathers: lane l -> edge slot (l>>1), half-row
// (l&1).  Per 16-edge csr window: 2 gather instrs (16 lanes x 16B) cover
// 16 edges x full row.  8-lane tree reduce; lanes 0/1 finalize 8 feats each.
// h2p[c] = bf16( dinv[c]*relu( dinv[c]*(sum h1p[src] + h1p[c]) + b1 ) )
__global__ __launch_bounds__(TPB) void gather1_kernel(const int* __restrict__ csr,
                                                      const int* __restrict__ offs,
                                                      const unsigned short* __restrict__ h1p,
                                                      const float* __restrict__ dinv,
                                                      const float* __restrict__ b1,
                                                      unsigned short* __restrict__ h2p, int N) {
    int t = threadIdx.x;
    int c = blockIdx.x * 16 + (t >> 4);
    int l = t & 15;
    int half = l & 1;                        // which 8-feature half-row
    int sub  = l >> 1;                       // edge slot 0..7
    if (c >= N) return;
    int p0 = offs[c], p1 = offs[c + 1];
    float a[8];
#pragma unroll
    for (int k = 0; k < 8; ++k) a[k] = 0.f;
    for (int p = p0; p < p1; p += 16) {
        int s16 = csr[min(p + l, p1 - 1)];
#pragma unroll
        for (int h = 0; h < 2; ++h) {
            int e = 8 * h + sub;
            int src = __shfl(s16, e, 16);
            unsigned int m = ((p + e) < p1) ? 0xffffffffu : 0u;
            uint4 v = *(const uint4*)&h1p[(size_t)src * 16 + 8 * half];
            bfacc8(v, m, a);
        }
    }
#pragma unroll
    for (int d = 2; d < 16; d <<= 1) {
#pragma unroll
        for (int k = 0; k < 8; ++k) a[k] += __shfl_xor(a[k], d, 16);
    }
    if (l < 2) {                             // l==half here
        float dc = dinv[c];
        uint4 sv = *(const uint4*)&h1p[(size_t)c * 16 + 8 * l];
        float sf[8];
        bfunp8(sv, sf);
        unsigned int uo[4];
#pragma unroll
        for (int q = 0; q < 4; ++q) {
            float r0 = fmaf(dc, a[2 * q] + sf[2 * q], b1[8 * l + 2 * q]);
            float r1 = fmaf(dc, a[2 * q + 1] + sf[2 * q + 1], b1[8 * l + 2 * q + 1]);
            r0 = dc * fmaxf(r0, 0.f);
            r1 = dc * fmaxf(r1, 0.f);
            uo[q] = (unsigned int)f2bf(r0) | ((unsigned int)f2bf(r1) << 16);
        }
        *(uint4*)&h2p[(size_t)c * 16 + 8 * l] = make_uint4(uo[0], uo[1], uo[2], uo[3]);
    }
}

// gather2f: fused gather2 + W2 matmul + sorted-batch pooling.  Block = 64 nodes.
// Phase 1: 16 groups x 16 lanes gather a2 rows (4 nodes/group, uint4 gathers
// as in gather1) into LDS asT.
// Phase 2: wave w: 64 lanes = output dims, 16 nodes from asT, W2 slice in regs,
//          run-accumulate; uniform-batch blocks pool in LDS, flush 64 atomics.
__global__ __launch_bounds__(TPB) void gather2f_kernel(
        const int* __restrict__ csr, const int* __restrict__ offs,
        const unsigned short* __restrict__ h2p, const float* __restrict__ dinv,
        const float* __restrict__ W2, const float* __restrict__ b2,
        const int* __restrict__ batch, float* __restrict__ out, int N) {
    __shared__ float w2s[16 * 64];
    __shared__ float asT[64 * 17];
    __shared__ float pool[64];
    int t = threadIdx.x;
    for (int i = t; i < 16 * 64; i += TPB) w2s[i] = W2[i];
    if (t < 64) pool[t] = 0.f;

    int n0 = blockIdx.x * 64;
    int nLast = min(n0 + 63, N - 1);
    int g0 = batch[n0];
    bool uniform = (batch[nLast] == g0);     // batch sorted

    // phase 1: gather (4 nodes per 16-lane group, uint4 loads)
    int grp = t >> 4, l = t & 15;
    int half = l & 1, sub = l >> 1;
#pragma unroll 1
    for (int it = 0; it < 4; ++it) {
        int m = grp * 4 + it;
        int c = n0 + m;
        if (c < N) {
            int p0 = offs[c], p1 = offs[c + 1];
            float a[8];
#pragma unroll
            for (int k = 0; k < 8; ++k) a[k] = 0.f;
            for (int p = p0; p < p1; p += 16) {
                int s16 = csr[min(p + l, p1 - 1)];
#pragma unroll
                for (int h = 0; h < 2; ++h) {
                    int e = 8 * h + sub;
                    int src = __shfl(s16, e, 16);
                    unsigned int mm = ((p + e) < p1) ? 0xffffffffu : 0u;
                    uint4 v = *(const uint4*)&h2p[(size_t)src * 16 + 8 * half];
                    bfacc8(v, mm, a);
                }
            }
#pragma unroll
            for (int d = 2; d < 16; d <<= 1) {
#pragma unroll
                for (int k = 0; k < 8; ++k) a[k] += __shfl_xor(a[k], d, 16);
            }
            if (l < 2) {
                float dc = dinv[c];
                uint4 sv = *(const uint4*)&h2p[(size_t)c * 16 + 8 * l];
                float sf[8];
                bfunp8(sv, sf);
#pragma unroll
                for (int k = 0; k < 8; ++k)
                    asT[m * 17 + 8 * l + k] = dc * (a[k] + sf[k]);
            }
        }
    }
    __syncthreads();

    // phase 2: wave w covers nodes n0+16w .. n0+16w+15
    int wave = t >> 6, j = t & 63;
    float w2reg[16];
#pragma unroll
    for (int kx = 0; kx < 16; ++kx) w2reg[kx] = w2s[kx * 64 + j];
    float b2j = b2[j];
    float val = 0.f;
    int g_cur = -1;
#pragma unroll 1
    for (int mi = 0; mi < 16; ++mi) {
        int m = wave * 16 + mi;
        int c = n0 + m;
        if (c >= N) break;
        const float* ar = &asT[m * 17];
        float y = b2j;
#pragma unroll
        for (int kx = 0; kx < 16; ++kx) y = fmaf(ar[kx], w2reg[kx], y);
        if (uniform) {
            val += y;
        } else {
            int g = batch[c];
            if (g != g_cur) {
                if (g_cur >= 0) atomicAdd(&out[(size_t)g_cur * 64 + j], val);
                val = 0.f;
                g_cur = g;
            }
            val += y;
        }
    }
    if (uniform) {
        atomicAdd(&pool[j], val);            // LDS, 4-way per address
        __syncthreads();
        if (t < 64) atomicAdd(&out[(size_t)g0 * 64 + t], pool[t]);
    } else {
        if (g_cur >= 0) atomicAdd(&out[(size_t)g_cur * 64 + j], val);
    }
}

static inline size_t align64(size_t v) { return (v + 63) & ~(size_t)63; }

extern "C" void kernel_launch(void* const* d_in, const int* in_sizes, int n_in,
                              void* d_out, int out_size, void* d_ws, size_t ws_size,
                              hipStream_t stream) {
    const float* x     = (const float*)d_in[0];
    const int*   ei    = (const int*)d_in[1];
    const int*   batch = (const int*)d_in[2];
    const float* W1    = (const float*)d_in[3];
    const float* b1    = (const float*)d_in[4];
    const float* W2    = (const float*)d_in[5];
    const float* b2    = (const float*)d_in[6];

    const int N = in_sizes[0] / 128;
    const int E = in_sizes[1] / 2;
    const int* row = ei;        // edge_index[0]
    const int* col = ei + E;    // edge_index[1]

    const int NBLK  = (E + CHUNK - 1) / CHUNK;       // 782
    const int NBUCK = (N + NPB - 1) / NPB;           // 391 (<=512)
    const int L     = NBUCK * NBLK;                  // 305762
    const int NBS   = (L + TPB - 1) / TPB;           // 1195 (<=2048 for scan2)
    const int NBG   = (N + TPB - 1) / TPB;           // 782

    char* p = (char*)d_ws;
    int*            counts   = (int*)p;            p += align64((size_t)L * 4);
    int*            bsum     = (int*)p;            p += align64(2048 * 4);
    int*            bucketed = (int*)p;            p += align64((size_t)E * 4);
    int*            csr      = (int*)p;            p += align64((size_t)E * 4);
    int*            offs     = (int*)p;            p += align64((size_t)(N + 1) * 4);
    float*          dinv     = (float*)p;          p += align64((size_t)N * 4);
    unsigned short* h1b      = (unsigned short*)p; p += align64((size_t)N * 16 * 2);
    unsigned short* h1p      = (unsigned short*)p; p += align64((size_t)N * 16 * 2);
    unsigned short* h2p      = (unsigned short*)p; p += align64((size_t)N * 16 * 2);
    float*          out      = (float*)d_out;

    hipMemsetAsync(out, 0, (size_t)out_size * sizeof(float), stream);

    hist_kernel<<<NBLK, TPB, 0, stream>>>(col, counts, E, NBLK, NBUCK);
    scan1_kernel<<<NBS, TPB, 0, stream>>>(counts, counts, bsum, L);
    scan2_kernel<<<1, 1024, 0, stream>>>(bsum, NBS);
    s1c_gemm_kernel<<<NBLK + NBG, TPB, 0, stream>>>(row, col, counts, bsum,
                                                    E, NBLK, NBUCK,
                                                    bucketed, x, W1, h1b, N, NBG);
    sort_kernel<<<NBUCK, TPB, 0, stream>>>(bucketed, counts, bsum, E, NBLK, NBUCK,
                                           csr, offs, dinv, h1b, h1p, N);
    gather1_kernel<<<(N + 15) / 16, TPB, 0, stream>>>(csr, offs, h1p, dinv, b1, h2p, N);
    gather2f_kernel<<<(N + 63) / 64, TPB, 0, stream>>>(csr, offs, h2p, dinv,
                                                       W2, b2, batch, out, N);
}

// Round 4
// 375.040 us; speedup vs baseline: 8.7888x; 8.7888x over previous
//
#include <hip/hip_runtime.h>

// 2-layer GCN, CSR-gather, bf16 payloads, zero global atomics.
//   hist(512-node buckets) -> scan1/scan2 -> [scatter ∥ gemm, 1:1] -> sort
//   -> gather1 -> gather2f (gather + W2 matmul + pooled output, fused).
// Kept: 1:1 scatter/gemm interleave (R9), 512-node buckets, packed 1-int
// bucket entries, bf16 h1 (R10), scan3g folded into consumers (R10),
// final fused into gather2 (R10), sorted coalesced bucket writes (R12),
// scan-diff counts + shfl scan + LDS union (R13), uint4 gathers (R13).
// R14: gemm x via coalesced LDS-staged K-chunks (4 lanes = one 64B line).
// R15: R14 spilled catastrophically (VGPR 256, 3GB scratch traffic): full
//      unroll of the chunk loop let the compiler hoist all 28 const-restrict
//      x loads above the barriers.  Fix: #pragma unroll 1 on the chunk loop
//      -> prefetch regs are loop-carried, exactly one chunk (4 float4) in
//      flight; schedule is now structural, not unroller-dependent.

#define TPB 256
#define CHUNK 4096          // edges per stage-1 block (1:1 with gemm blocks)
#define BK_SHIFT 9
#define NPB 512             // nodes per bucket = 1 << BK_SHIFT
#define XSL 260             // xs row stride in floats (bank-spread pad)

__device__ __forceinline__ float bf2f(unsigned short u) {
    union { unsigned int i; float f; } v; v.i = ((unsigned int)u) << 16; return v.f;
}
__device__ __forceinline__ unsigned short f2bf(float f) {
    union { float f; unsigned int i; } v; v.f = f;
    unsigned int r = v.i + 0x7fff + ((v.i >> 16) & 1);   // RNE
    return (unsigned short)(r >> 16);
}
// accumulate 8 bf16 (one uint4) into a[0..7]; mask kills invalid edges
__device__ __forceinline__ void bfacc8(uint4 v, unsigned int m, float* a) {
    union { unsigned int i; float f; } lo, hi;
    v.x &= m; v.y &= m; v.z &= m; v.w &= m;
    lo.i = v.x << 16; hi.i = v.x & 0xffff0000u; a[0] += lo.f; a[1] += hi.f;
    lo.i = v.y << 16; hi.i = v.y & 0xffff0000u; a[2] += lo.f; a[3] += hi.f;
    lo.i = v.z << 16; hi.i = v.z & 0xffff0000u; a[4] += lo.f; a[5] += hi.f;
    lo.i = v.w << 16; hi.i = v.w & 0xffff0000u; a[6] += lo.f; a[7] += hi.f;
}
__device__ __forceinline__ void bfunp8(uint4 v, float* a) {
    union { unsigned int i; float f; } lo, hi;
    lo.i = v.x << 16; hi.i = v.x & 0xffff0000u; a[0] = lo.f; a[1] = hi.f;
    lo.i = v.y << 16; hi.i = v.y & 0xffff0000u; a[2] = lo.f; a[3] = hi.f;
    lo.i = v.z << 16; hi.i = v.z & 0xffff0000u; a[4] = lo.f; a[5] = hi.f;
    lo.i = v.w << 16; hi.i = v.w & 0xffff0000u; a[6] = lo.f; a[7] = hi.f;
}

// S1a: counts[bk*nblk + blk] = #edges in block blk with col>>9 == bk
__global__ __launch_bounds__(TPB) void hist_kernel(const int* __restrict__ col,
                                                   int* __restrict__ counts,
                                                   int E, int nblk, int nbuck) {
    __shared__ int hist[512];
    int t = threadIdx.x;
    for (int i = t; i < nbuck; i += TPB) hist[i] = 0;
    __syncthreads();
    int e0 = blockIdx.x * CHUNK;
    for (int i = t; i < CHUNK; i += TPB) {
        int e = e0 + i;
        if (e < E) atomicAdd(&hist[col[e] >> BK_SHIFT], 1);   // LDS atomic
    }
    __syncthreads();
    for (int i = t; i < nbuck; i += TPB) counts[i * nblk + blockIdx.x] = hist[i];
}

// scan1: per-256-block exclusive scan (counts in place), bsum[b]=block total
__global__ __launch_bounds__(TPB) void scan1_kernel(const int* __restrict__ in,
                                                    int* __restrict__ out,
                                                    int* __restrict__ bsum, int L) {
    __shared__ int s[TPB];
    int t = threadIdx.x;
    int i = blockIdx.x * TPB + t;
    int d = (i < L) ? in[i] : 0;
    s[t] = d; __syncthreads();
    for (int off = 1; off < TPB; off <<= 1) {
        int v = (t >= off) ? s[t - off] : 0;
        __syncthreads();
        s[t] += v;
        __syncthreads();
    }
    if (i < L) out[i] = s[t] - d;
    if (t == TPB - 1) bsum[blockIdx.x] = s[t];
}

// scan2: single-block exclusive scan of up to 2048 block sums (2 elems/thread)
__global__ __launch_bounds__(1024) void scan2_kernel(int* __restrict__ bsum, int nb) {
    __shared__ int s[1024];
    int t = threadIdx.x;
    int i0 = t * 2, i1 = t * 2 + 1;
    int v0 = (i0 < nb) ? bsum[i0] : 0;
    int v1 = (i1 < nb) ? bsum[i1] : 0;
    int pv = v0 + v1;
    s[t] = pv; __syncthreads();
    for (int off = 1; off < 1024; off <<= 1) {
        int u = (t >= off) ? s[t - off] : 0;
        __syncthreads();
        s[t] += u;
        __syncthreads();
    }
    int exc = s[t] - pv;
    if (i0 < nb) bsum[i0] = exc;
    if (i1 < nb) bsum[i1] = exc + v0;
}

// cbase[f] = counts[f] + bsum[f>>8]   (scan3g folded into consumers)
__device__ __forceinline__ int cbase_at(const int* counts, const int* bsum, int f) {
    return counts[f] + bsum[f >> 8];
}

// one 16-col window of the x@W1 microkernel
#define GEMM_W16(XV, GB)                                                          \
    {                                                                             \
        _Pragma("unroll")                                                         \
        for (int cc = 0; cc < 16; ++cc) {                                         \
            const float4* w4 = (const float4*)&w1s[((GB) * 16 + cc) * 16];        \
            float4 wa = w4[0], wb = w4[1], wc = w4[2], wd = w4[3];                \
            float xc = (XV)[cc];                                                  \
            acc[0]  = fmaf(xc, wa.x, acc[0]);  acc[1]  = fmaf(xc, wa.y, acc[1]);  \
            acc[2]  = fmaf(xc, wa.z, acc[2]);  acc[3]  = fmaf(xc, wa.w, acc[3]);  \
            acc[4]  = fmaf(xc, wb.x, acc[4]);  acc[5]  = fmaf(xc, wb.y, acc[5]);  \
            acc[6]  = fmaf(xc, wb.z, acc[6]);  acc[7]  = fmaf(xc, wb.w, acc[7]);  \
            acc[8]  = fmaf(xc, wc.x, acc[8]);  acc[9]  = fmaf(xc, wc.y, acc[9]);  \
            acc[10] = fmaf(xc, wc.z, acc[10]); acc[11] = fmaf(xc, wc.w, acc[11]); \
            acc[12] = fmaf(xc, wd.x, acc[12]); acc[13] = fmaf(xc, wd.y, acc[13]); \
            acc[14] = fmaf(xc, wd.z, acc[14]); acc[15] = fmaf(xc, wd.w, acc[15]); \
        }                                                                         \
    }

// cooperative coalesced load of K-chunk c into 4 float4 regs
#define LOADC(DST, C)                                                             \
    {                                                                             \
        _Pragma("unroll")                                                         \
        for (int it = 0; it < 4; ++it) {                                          \
            int idx = it * 256 + t;                                               \
            int r = idx >> 2, j = idx & 3;                                        \
            size_t gr = (size_t)min(n0g + r, N - 1);                              \
            DST[it] = xg4[gr * 32 + (size_t)((C) * 4 + j)];                       \
        }                                                                         \
    }
// transposed store: xs[kk][row], kk = j*4+q  (2 lanes/bank per instr = free)
#define STOREC(SRC)                                                               \
    {                                                                             \
        _Pragma("unroll")                                                         \
        for (int it = 0; it < 4; ++it) {                                          \
            int idx = it * 256 + t;                                               \
            int r = idx >> 2, j = idx & 3;                                        \
            float4 v = SRC[it];                                                   \
            xs[(j * 4 + 0) * XSL + r] = v.x;                                      \
            xs[(j * 4 + 1) * XSL + r] = v.y;                                      \
            xs[(j * 4 + 2) * XSL + r] = v.z;                                      \
            xs[(j * 4 + 3) * XSL + r] = v.w;                                      \
        }                                                                         \
    }

// S1c ∥ gemm, block-interleaved 1:1.
// Scatter: counts from scan diffs, shfl-scan local offsets, LDS counting
//   sort, bucket-ordered coalesced writes.
// Gemm: coalesced LDS-staged x chunks, unroll-1 pipelined (R15).
__global__ __launch_bounds__(TPB) void s1c_gemm_kernel(
        const int* __restrict__ row, const int* __restrict__ col,
        const int* __restrict__ counts, const int* __restrict__ bsum,
        int E, int nblk, int nbuck,
        int* __restrict__ bucketed,
        const float* __restrict__ x, const float* __restrict__ W1,
        unsigned short* __restrict__ h1b, int N, int nbg) {
    // unioned LDS: scatter uses 12352 B, gemm uses 8192 + 16640 B
    __shared__ __align__(16) char sbuf[8192 + 16 * XSL * 4];
    int* slhist = (int*)sbuf;                               // 512 ints (cursor)
    int* sgd    = (int*)(sbuf + 2048);                      // 512 ints
    unsigned short* ssidx = (unsigned short*)(sbuf + 4096); // 4096 ushort
    int* swtot  = (int*)(sbuf + 4096 + 8192);               // 4 ints
    float* w1s  = (float*)sbuf;                             // gemm: 8 KB
    float* xs   = (float*)(sbuf + 8192);                    // gemm: 16x260 f32

    int b = (int)blockIdx.x, t = threadIdx.x;
    int M = min(nblk, nbg);
    int role, id;
    if (b < 2 * M) { role = b & 1; id = b >> 1; }
    else           { role = (nblk > nbg) ? 0 : 1; id = b - M; }

    if (role == 0) {                         // block-local counting sort
        int e0 = id * CHUNK;
        int nE = min(CHUNK, E - e0);
        int Ltot = nbuck * nblk;
        int lane = t & 63, w = t >> 6;
        int bk0 = 2 * t, bk1 = 2 * t + 1;
        // per-bin counts for this chunk from global-scan differences
        int cb0 = 0, cb1 = 0, c0 = 0, c1 = 0;
        if (bk0 < nbuck) {
            int f = bk0 * nblk + id;
            cb0 = cbase_at(counts, bsum, f);
            int nx = (f + 1 < Ltot) ? cbase_at(counts, bsum, f + 1) : E;
            c0 = nx - cb0;
        }
        if (bk1 < nbuck) {
            int f = bk1 * nblk + id;
            cb1 = cbase_at(counts, bsum, f);
            int nx = (f + 1 < Ltot) ? cbase_at(counts, bsum, f + 1) : E;
            c1 = nx - cb1;
        }
        int s = c0 + c1;
        // wave inclusive scan of s over 64 lanes (bin order == thread order)
        int v = s;
#pragma unroll
        for (int d = 1; d < 64; d <<= 1) {
            int u2 = __shfl_up(v, d, 64);
            if (lane >= d) v += u2;
        }
        if (lane == 63) swtot[w] = v;
        __syncthreads();
        int wbase = 0;
#pragma unroll
        for (int i = 0; i < 4; ++i) wbase += (i < w) ? swtot[i] : 0;
        int o0 = wbase + v - s;              // local exclusive start of bk0
        int o1 = o0 + c0;
        if (bk0 < nbuck) { slhist[bk0] = o0; sgd[bk0] = cb0 - o0; }
        if (bk1 < nbuck) { slhist[bk1] = o1; sgd[bk1] = cb1 - o1; }
        __syncthreads();
        // scatter chunk-local indices into sorted order
        for (int i = t; i < nE; i += TPB) {
            int c = col[e0 + i];
            int lp = atomicAdd(&slhist[c >> BK_SHIFT], 1);     // LDS atomic
            ssidx[lp] = (unsigned short)i;
        }
        __syncthreads();
        // write out in bucket order -> runs of consecutive addresses
        for (int j = t; j < nE; j += TPB) {
            int i = ssidx[j];
            int c = col[e0 + i];                               // L1/L2-hot
            int r = row[e0 + i];
            bucketed[sgd[c >> BK_SHIFT] + j] = ((c & (NPB - 1)) << 18) | r;
        }
        return;
    }
    // gemm: h1b[n] = bf16(x[n] @ W1), LDS-staged coalesced x, W1 in LDS
    for (int i = t; i < 128 * 16; i += TPB) w1s[i] = W1[i];
    int n0g = id * TPB;
    int n = n0g + t;
    const float4* xg4 = (const float4*)x;
    float acc[16];
#pragma unroll
    for (int k = 0; k < 16; ++k) acc[k] = 0.f;
    float4 st[4];
    LOADC(st, 0);
    STOREC(st);
#pragma unroll 1
    for (int c = 0; c < 8; ++c) {            // unroll 1: one chunk in flight,
        float4 nx[4];                        //   prefetch regs loop-carried
        if (c < 7) LOADC(nx, c + 1);         // issue before barrier: latency
        __syncthreads();                     //   hides under this chunk's FMAs
        float xv[16];
#pragma unroll
        for (int kk = 0; kk < 16; ++kk) xv[kk] = xs[kk * XSL + t];
        GEMM_W16(xv, c);
        __syncthreads();                     // reads done before overwrite
        if (c < 7) STOREC(nx);
    }
    if (n < N) {
        unsigned int u[8];
#pragma unroll
        for (int j = 0; j < 8; ++j)
            u[j] = (unsigned int)f2bf(acc[2 * j]) | ((unsigned int)f2bf(acc[2 * j + 1]) << 16);
        uint4* o = (uint4*)(h1b + (size_t)n * 16);
        o[0] = make_uint4(u[0], u[1], u[2], u[3]);
        o[1] = make_uint4(u[4], u[5], u[6], u[7]);
    }
}

// S2: one block per 512-node bucket: counting sort, emit csr/offs/dinv,
// h1p = bf16(dinv * h1b).
__global__ __launch_bounds__(TPB) void sort_kernel(
        const int* __restrict__ bucketed,
        const int* __restrict__ counts, const int* __restrict__ bsum,
        int E, int nblk, int nbuck,
        int* __restrict__ csr, int* __restrict__ offs, float* __restrict__ dinv,
        const unsigned short* __restrict__ h1b, unsigned short* __restrict__ h1p, int N) {
    __shared__ int lhist[NPB];
    __shared__ int part[TPB];
    __shared__ float sdinv[NPB];
    int bk = blockIdx.x, t = threadIdx.x;
    int n0 = bk << BK_SHIFT;
    int n1 = min(n0 + NPB, N);
    int e0 = cbase_at(counts, bsum, bk * nblk);
    int e1 = (bk + 1 < nbuck) ? cbase_at(counts, bsum, (bk + 1) * nblk) : E;

    lhist[t] = 0; lhist[t + TPB] = 0;
    __syncthreads();
    for (int i = e0 + t; i < e1; i += TPB)
        atomicAdd(&lhist[bucketed[i] >> 18], 1);               // LDS atomic
    __syncthreads();

    int base = t * 2;
    int c0 = lhist[base], c1 = lhist[base + 1];
    int s = c0 + c1;
    part[t] = s;
    __syncthreads();
    for (int off = 1; off < TPB; off <<= 1) {
        int v = (t >= off) ? part[t - off] : 0;
        __syncthreads();
        part[t] += v;
        __syncthreads();
    }
    int o0 = e0 + part[t] - s;
    int o1 = o0 + c0;
    lhist[base] = o0; lhist[base + 1] = o1;
    sdinv[base]     = rsqrtf((float)c0 + 1.0f);
    sdinv[base + 1] = rsqrtf((float)c1 + 1.0f);
    int n = n0 + base;
    if (n + 0 < N) { offs[n + 0] = o0; dinv[n + 0] = sdinv[base]; }
    if (n + 1 < N) { offs[n + 1] = o1; dinv[n + 1] = sdinv[base + 1]; }
    __syncthreads();

    for (int i = e0 + t; i < e1; i += TPB) {
        int v = bucketed[i];
        int pos = atomicAdd(&lhist[v >> 18], 1);               // LDS atomic
        csr[pos] = v & 0x3FFFF;
    }
    int nq = (n1 - n0) * 4;                  // one quad (4 feats) per i
    for (int i = t; i < nq; i += TPB) {
        float dv = sdinv[i >> 2];
        uint2 u = ((const uint2*)h1b)[(size_t)n0 * 4 + i];
        float f0 = bf2f((unsigned short)(u.x & 0xffff));
        float f1 = bf2f((unsigned short)(u.x >> 16));
        float f2 = bf2f((unsigned short)(u.y & 0xffff));
        float f3 = bf2f((unsigned short)(u.y >> 16));
        ((ushort4*)h1p)[(size_t)n0 * 4 + i] =
            make_ushort4(f2bf(f0 * dv), f2bf(f1 * dv), f2bf(f2 * dv), f2bf(f3 * dv));
    }
    if (bk == 0 && t == 0) offs[N] = E;
}

// gather1: 16 lanes/node, uint4 gathers: lane l -> edge slot (l>>1), half-row
// (l&1).  Per 16-edge csr window: 2 gather instrs (16 lanes x 16B) cover
// 16 edges x full row.  8-lane tree reduce; lanes 0/1 finalize 8 feats each.
// h2p[c] = bf16( dinv[c]*relu( dinv[c]*(sum h1p[src] + h1p[c]) + b1 ) )
__global__ __launch_bounds__(TPB) void gather1_kernel(const int* __restrict__ csr,
                                                      const int* __restrict__ offs,
                                                      const unsigned short* __restrict__ h1p,
                                                      const float* __restrict__ dinv,
                                                      const float* __restrict__ b1,
                                                      unsigned short* __restrict__ h2p, int N) {
    int t = threadIdx.x;
    int c = blockIdx.x * 16 + (t >> 4);
    int l = t & 15;
    int half = l & 1;                        // which 8-feature half-row
    int sub  = l >> 1;                       // edge slot 0..7
    if (c >= N) return;
    int p0 = offs[c], p1 = offs[c + 1];
    float a[8];
#pragma unroll
    for (int k = 0; k < 8; ++k) a[k] = 0.f;
    for (int p = p0; p < p1; p += 16) {
        int s16 = csr[min(p + l, p1 - 1)];
#pragma unroll
        for (int h = 0; h < 2; ++h) {
            int e = 8 * h + sub;
            int src = __shfl(s16, e, 16);
            unsigned int m = ((p + e) < p1) ? 0xffffffffu : 0u;
            uint4 v = *(const uint4*)&h1p[(size_t)src * 16 + 8 * half];
            bfacc8(v, m, a);
        }
    }
#pragma unroll
    for (int d = 2; d < 16; d <<= 1) {
#pragma unroll
        for (int k = 0; k < 8; ++k) a[k] += __shfl_xor(a[k], d, 16);
    }
    if (l < 2) {                             // l==half here
        float dc = dinv[c];
        uint4 sv = *(const uint4*)&h1p[(size_t)c * 16 + 8 * l];
        float sf[8];
        bfunp8(sv, sf);
        unsigned int uo[4];
#pragma unroll
        for (int q = 0; q < 4; ++q) {
            float r0 = fmaf(dc, a[2 * q] + sf[2 * q], b1[8 * l + 2 * q]);
            float r1 = fmaf(dc, a[2 * q + 1] + sf[2 * q + 1], b1[8 * l + 2 * q + 1]);
            r0 = dc * fmaxf(r0, 0.f);
            r1 = dc * fmaxf(r1, 0.f);
            uo[q] = (unsigned int)f2bf(r0) | ((unsigned int)f2bf(r1) << 16);
        }
        *(uint4*)&h2p[(size_t)c * 16 + 8 * l] = make_uint4(uo[0], uo[1], uo[2], uo[3]);
    }
}

// gather2f: fused gather2 + W2 matmul + sorted-batch pooling.  Block = 64 nodes.
// Phase 1: 16 groups x 16 lanes gather a2 rows (4 nodes/group, uint4 gathers
// as in gather1) into LDS asT.
// Phase 2: wave w: 64 lanes = output dims, 16 nodes from asT, W2 slice in regs,
//          run-accumulate; uniform-batch blocks pool in LDS, flush 64 atomics.
__global__ __launch_bounds__(TPB) void gather2f_kernel(
        const int* __restrict__ csr, const int* __restrict__ offs,
        const unsigned short* __restrict__ h2p, const float* __restrict__ dinv,
        const float* __restrict__ W2, const float* __restrict__ b2,
        const int* __restrict__ batch, float* __restrict__ out, int N) {
    __shared__ float w2s[16 * 64];
    __shared__ float asT[64 * 17];
    __shared__ float pool[64];
    int t = threadIdx.x;
    for (int i = t; i < 16 * 64; i += TPB) w2s[i] = W2[i];
    if (t < 64) pool[t] = 0.f;

    int n0 = blockIdx.x * 64;
    int nLast = min(n0 + 63, N - 1);
    int g0 = batch[n0];
    bool uniform = (batch[nLast] == g0);     // batch sorted

    // phase 1: gather (4 nodes per 16-lane group, uint4 loads)
    int grp = t >> 4, l = t & 15;
    int half = l & 1, sub = l >> 1;
#pragma unroll 1
    for (int it = 0; it < 4; ++it) {
        int m = grp * 4 + it;
        int c = n0 + m;
        if (c < N) {
            int p0 = offs[c], p1 = offs[c + 1];
            float a[8];
#pragma unroll
            for (int k = 0; k < 8; ++k) a[k] = 0.f;
            for (int p = p0; p < p1; p += 16) {
                int s16 = csr[min(p + l, p1 - 1)];
#pragma unroll
                for (int h = 0; h < 2; ++h) {
                    int e = 8 * h + sub;
                    int src = __shfl(s16, e, 16);
                    unsigned int mm = ((p + e) < p1) ? 0xffffffffu : 0u;
                    uint4 v = *(const uint4*)&h2p[(size_t)src * 16 + 8 * half];
                    bfacc8(v, mm, a);
                }
            }
#pragma unroll
            for (int d = 2; d < 16; d <<= 1) {
#pragma unroll
                for (int k = 0; k < 8; ++k) a[k] += __shfl_xor(a[k], d, 16);
            }
            if (l < 2) {
                float dc = dinv[c];
                uint4 sv = *(const uint4*)&h2p[(size_t)c * 16 + 8 * l];
                float sf[8];
                bfunp8(sv, sf);
#pragma unroll
                for (int k = 0; k < 8; ++k)
                    asT[m * 17 + 8 * l + k] = dc * (a[k] + sf[k]);
            }
        }
    }
    __syncthreads();

    // phase 2: wave w covers nodes n0+16w .. n0+16w+15
    int wave = t >> 6, j = t & 63;
    float w2reg[16];
#pragma unroll
    for (int kx = 0; kx < 16; ++kx) w2reg[kx] = w2s[kx * 64 + j];
    float b2j = b2[j];
    float val = 0.f;
    int g_cur = -1;
#pragma unroll 1
    for (int mi = 0; mi < 16; ++mi) {
        int m = wave * 16 + mi;
        int c = n0 + m;
        if (c >= N) break;
        const float* ar = &asT[m * 17];
        float y = b2j;
#pragma unroll
        for (int kx = 0; kx < 16; ++kx) y = fmaf(ar[kx], w2reg[kx], y);
        if (uniform) {
            val += y;
        } else {
            int g = batch[c];
            if (g != g_cur) {
                if (g_cur >= 0) atomicAdd(&out[(size_t)g_cur * 64 + j], val);
                val = 0.f;
                g_cur = g;
            }
            val += y;
        }
    }
    if (uniform) {
        atomicAdd(&pool[j], val);            // LDS, 4-way per address
        __syncthreads();
        if (t < 64) atomicAdd(&out[(size_t)g0 * 64 + t], pool[t]);
    } else {
        if (g_cur >= 0) atomicAdd(&out[(size_t)g_cur * 64 + j], val);
    }
}

static inline size_t align64(size_t v) { return (v + 63) & ~(size_t)63; }

extern "C" void kernel_launch(void* const* d_in, const int* in_sizes, int n_in,
                              void* d_out, int out_size, void* d_ws, size_t ws_size,
                              hipStream_t stream) {
    const float* x     = (const float*)d_in[0];
    const int*   ei    = (const int*)d_in[1];
    const int*   batch = (const int*)d_in[2];
    const float* W1    = (const float*)d_in[3];
    const float* b1    = (const float*)d_in[4];
    const float* W2    = (const float*)d_in[5];
    const float* b2    = (const float*)d_in[6];

    const int N = in_sizes[0] / 128;
    const int E = in_sizes[1] / 2;
    const int* row = ei;        // edge_index[0]
    const int* col = ei + E;    // edge_index[1]

    const int NBLK  = (E + CHUNK - 1) / CHUNK;       // 782
    const int NBUCK = (N + NPB - 1) / NPB;           // 391 (<=512)
    const int L     = NBUCK * NBLK;                  // 305762
    const int NBS   = (L + TPB - 1) / TPB;           // 1195 (<=2048 for scan2)
    const int NBG   = (N + TPB - 1) / TPB;           // 782

    char* p = (char*)d_ws;
    int*            counts   = (int*)p;            p += align64((size_t)L * 4);
    int*            bsum     = (int*)p;            p += align64(2048 * 4);
    int*            bucketed = (int*)p;            p += align64((size_t)E * 4);
    int*            csr      = (int*)p;            p += align64((size_t)E * 4);
    int*            offs     = (int*)p;            p += align64((size_t)(N + 1) * 4);
    float*          dinv     = (float*)p;          p += align64((size_t)N * 4);
    unsigned short* h1b      = (unsigned short*)p; p += align64((size_t)N * 16 * 2);
    unsigned short* h1p      = (unsigned short*)p; p += align64((size_t)N * 16 * 2);
    unsigned short* h2p      = (unsigned short*)p; p += align64((size_t)N * 16 * 2);
    float*          out      = (float*)d_out;

    hipMemsetAsync(out, 0, (size_t)out_size * sizeof(float), stream);

    hist_kernel<<<NBLK, TPB, 0, stream>>>(col, counts, E, NBLK, NBUCK);
    scan1_kernel<<<NBS, TPB, 0, stream>>>(counts, counts, bsum, L);
    scan2_kernel<<<1, 1024, 0, stream>>>(bsum, NBS);
    s1c_gemm_kernel<<<NBLK + NBG, TPB, 0, stream>>>(row, col, counts, bsum,
                                                    E, NBLK, NBUCK,
                                                    bucketed, x, W1, h1b, N, NBG);
    sort_kernel<<<NBUCK, TPB, 0, stream>>>(bucketed, counts, bsum, E, NBLK, NBUCK,
                                           csr, offs, dinv, h1b, h1p, N);
    gather1_kernel<<<(N + 15) / 16, TPB, 0, stream>>>(csr, offs, h1p, dinv, b1, h2p, N);
    gather2f_kernel<<<(N + 63) / 64, TPB, 0, stream>>>(csr, offs, h2p, dinv,
                                                       W2, b2, batch, out, N);
}

// Round 5
// 342.557 us; speedup vs baseline: 9.6222x; 1.0948x over previous
//
#include <hip/hip_runtime.h>

// 2-layer GCN, CSR-gather, bf16 payloads, zero global atomics.
//   hist(512-node buckets) -> scan1/scan2 -> [scatter ∥ gemm, 1:1] -> sort
//   -> gather1 -> gather2f (gather + W2 matmul + pooled output, fused).
// Kept: 1:1 scatter/gemm interleave (R9), 512-node buckets, packed 1-int
// bucket entries, bf16 h1 (R10), scan3g folded into consumers (R10),
// final fused into gather2 (R10), sorted coalesced bucket writes (R12),
// scan-diff counts + shfl scan + LDS union (R13), uint4 gathers (R13).
// R14/R15 history: LDS-staged coalesced x (R14 spilled: full unroll hoisted
//   28 loads, VGPR 256, 3GB scratch; R15 fixed spill but the barrier-chained
//   pipeline at 4 waves/block cost more than the latency win: 93->110us).
// R16: gemm role = 4 threads per node, K-split.  Thread q loads xr[i*4+q]
//   (fixed i: 4 consecutive lanes = one full 64B line -> 16 lines/instr,
//   same coalescing as R15) with ZERO barriers and no x-staging; 8
//   independent loads in flight; 512 FMA/thread into acc[16]; 2-step
//   shfl_xor(width=4) butterfly; lane q stores its 8B slice of the bf16
//   row.  W1 in LDS at stride-20 floats: q-lanes' k-offsets (dk=4 ->
//   +320B -> bank+16) land 2-way on banks = free (m136).

#define TPB 256
#define CHUNK 4096          // edges per stage-1 block
#define BK_SHIFT 9
#define NPB 512             // nodes per bucket = 1 << BK_SHIFT
#define W1S 20              // w1s k-row stride in floats (bank-spread pad)

__device__ __forceinline__ float bf2f(unsigned short u) {
    union { unsigned int i; float f; } v; v.i = ((unsigned int)u) << 16; return v.f;
}
__device__ __forceinline__ unsigned short f2bf(float f) {
    union { float f; unsigned int i; } v; v.f = f;
    unsigned int r = v.i + 0x7fff + ((v.i >> 16) & 1);   // RNE
    return (unsigned short)(r >> 16);
}
// accumulate 8 bf16 (one uint4) into a[0..7]; mask kills invalid edges
__device__ __forceinline__ void bfacc8(uint4 v, unsigned int m, float* a) {
    union { unsigned int i; float f; } lo, hi;
    v.x &= m; v.y &= m; v.z &= m; v.w &= m;
    lo.i = v.x << 16; hi.i = v.x & 0xffff0000u; a[0] += lo.f; a[1] += hi.f;
    lo.i = v.y << 16; hi.i = v.y & 0xffff0000u; a[2] += lo.f; a[3] += hi.f;
    lo.i = v.z << 16; hi.i = v.z & 0xffff0000u; a[4] += lo.f; a[5] += hi.f;
    lo.i = v.w << 16; hi.i = v.w & 0xffff0000u; a[6] += lo.f; a[7] += hi.f;
}
__device__ __forceinline__ void bfunp8(uint4 v, float* a) {
    union { unsigned int i; float f; } lo, hi;
    lo.i = v.x << 16; hi.i = v.x & 0xffff0000u; a[0] = lo.f; a[1] = hi.f;
    lo.i = v.y << 16; hi.i = v.y & 0xffff0000u; a[2] = lo.f; a[3] = hi.f;
    lo.i = v.z << 16; hi.i = v.z & 0xffff0000u; a[4] = lo.f; a[5] = hi.f;
    lo.i = v.w << 16; hi.i = v.w & 0xffff0000u; a[6] = lo.f; a[7] = hi.f;
}

// S1a: counts[bk*nblk + blk] = #edges in block blk with col>>9 == bk
__global__ __launch_bounds__(TPB) void hist_kernel(const int* __restrict__ col,
                                                   int* __restrict__ counts,
                                                   int E, int nblk, int nbuck) {
    __shared__ int hist[512];
    int t = threadIdx.x;
    for (int i = t; i < nbuck; i += TPB) hist[i] = 0;
    __syncthreads();
    int e0 = blockIdx.x * CHUNK;
    for (int i = t; i < CHUNK; i += TPB) {
        int e = e0 + i;
        if (e < E) atomicAdd(&hist[col[e] >> BK_SHIFT], 1);   // LDS atomic
    }
    __syncthreads();
    for (int i = t; i < nbuck; i += TPB) counts[i * nblk + blockIdx.x] = hist[i];
}

// scan1: per-256-block exclusive scan (counts in place), bsum[b]=block total
__global__ __launch_bounds__(TPB) void scan1_kernel(const int* __restrict__ in,
                                                    int* __restrict__ out,
                                                    int* __restrict__ bsum, int L) {
    __shared__ int s[TPB];
    int t = threadIdx.x;
    int i = blockIdx.x * TPB + t;
    int d = (i < L) ? in[i] : 0;
    s[t] = d; __syncthreads();
    for (int off = 1; off < TPB; off <<= 1) {
        int v = (t >= off) ? s[t - off] : 0;
        __syncthreads();
        s[t] += v;
        __syncthreads();
    }
    if (i < L) out[i] = s[t] - d;
    if (t == TPB - 1) bsum[blockIdx.x] = s[t];
}

// scan2: single-block exclusive scan of up to 2048 block sums (2 elems/thread)
__global__ __launch_bounds__(1024) void scan2_kernel(int* __restrict__ bsum, int nb) {
    __shared__ int s[1024];
    int t = threadIdx.x;
    int i0 = t * 2, i1 = t * 2 + 1;
    int v0 = (i0 < nb) ? bsum[i0] : 0;
    int v1 = (i1 < nb) ? bsum[i1] : 0;
    int pv = v0 + v1;
    s[t] = pv; __syncthreads();
    for (int off = 1; off < 1024; off <<= 1) {
        int u = (t >= off) ? s[t - off] : 0;
        __syncthreads();
        s[t] += u;
        __syncthreads();
    }
    int exc = s[t] - pv;
    if (i0 < nb) bsum[i0] = exc;
    if (i1 < nb) bsum[i1] = exc + v0;
}

// cbase[f] = counts[f] + bsum[f>>8]   (scan3g folded into consumers)
__device__ __forceinline__ int cbase_at(const int* counts, const int* bsum, int f) {
    return counts[f] + bsum[f >> 8];
}

// S1c ∥ gemm, block-interleaved 1:1.
// Scatter: counts from scan diffs, shfl-scan local offsets, LDS counting
//   sort, bucket-ordered coalesced writes.
// Gemm: 4 threads/node K-split, coalesced line loads, no barriers (R16).
__global__ __launch_bounds__(TPB) void s1c_gemm_kernel(
        const int* __restrict__ row, const int* __restrict__ col,
        const int* __restrict__ counts, const int* __restrict__ bsum,
        int E, int nblk, int nbuck,
        int* __restrict__ bucketed,
        const float* __restrict__ x, const float* __restrict__ W1,
        unsigned short* __restrict__ h1b, int N, int nbg) {
    // unioned LDS: scatter uses 12352 B, gemm uses 10240 B (w1s stride-20)
    __shared__ __align__(16) char sbuf[2048 + 2048 + 8192 + 64];
    int* slhist = (int*)sbuf;                               // 512 ints (cursor)
    int* sgd    = (int*)(sbuf + 2048);                      // 512 ints
    unsigned short* ssidx = (unsigned short*)(sbuf + 4096); // 4096 ushort
    int* swtot  = (int*)(sbuf + 4096 + 8192);               // 4 ints
    float* w1s  = (float*)sbuf;                             // gemm: 128x20 f32

    int b = (int)blockIdx.x, t = threadIdx.x;
    int M = min(nblk, nbg);
    int role, id;
    if (b < 2 * M) { role = b & 1; id = b >> 1; }
    else           { role = (nblk > nbg) ? 0 : 1; id = b - M; }

    if (role == 0) {                         // block-local counting sort
        int e0 = id * CHUNK;
        int nE = min(CHUNK, E - e0);
        int Ltot = nbuck * nblk;
        int lane = t & 63, w = t >> 6;
        int bk0 = 2 * t, bk1 = 2 * t + 1;
        // per-bin counts for this chunk from global-scan differences
        int cb0 = 0, cb1 = 0, c0 = 0, c1 = 0;
        if (bk0 < nbuck) {
            int f = bk0 * nblk + id;
            cb0 = cbase_at(counts, bsum, f);
            int nx = (f + 1 < Ltot) ? cbase_at(counts, bsum, f + 1) : E;
            c0 = nx - cb0;
        }
        if (bk1 < nbuck) {
            int f = bk1 * nblk + id;
            cb1 = cbase_at(counts, bsum, f);
            int nx = (f + 1 < Ltot) ? cbase_at(counts, bsum, f + 1) : E;
            c1 = nx - cb1;
        }
        int s = c0 + c1;
        // wave inclusive scan of s over 64 lanes (bin order == thread order)
        int v = s;
#pragma unroll
        for (int d = 1; d < 64; d <<= 1) {
            int u2 = __shfl_up(v, d, 64);
            if (lane >= d) v += u2;
        }
        if (lane == 63) swtot[w] = v;
        __syncthreads();
        int wbase = 0;
#pragma unroll
        for (int i = 0; i < 4; ++i) wbase += (i < w) ? swtot[i] : 0;
        int o0 = wbase + v - s;              // local exclusive start of bk0
        int o1 = o0 + c0;
        if (bk0 < nbuck) { slhist[bk0] = o0; sgd[bk0] = cb0 - o0; }
        if (bk1 < nbuck) { slhist[bk1] = o1; sgd[bk1] = cb1 - o1; }
        __syncthreads();
        // scatter chunk-local indices into sorted order
        for (int i = t; i < nE; i += TPB) {
            int c = col[e0 + i];
            int lp = atomicAdd(&slhist[c >> BK_SHIFT], 1);     // LDS atomic
            ssidx[lp] = (unsigned short)i;
        }
        __syncthreads();
        // write out in bucket order -> runs of consecutive addresses
        for (int j = t; j < nE; j += TPB) {
            int i = ssidx[j];
            int c = col[e0 + i];                               // L1/L2-hot
            int r = row[e0 + i];
            bucketed[sgd[c >> BK_SHIFT] + j] = ((c & (NPB - 1)) << 18) | r;
        }
        return;
    }
    // gemm: h1b[n] = bf16(x[n] @ W1).  4 threads/node, thread q covers
    // k in {16i+4q+j}; per-i loads are 64B-line coalesced across q.
    for (int i = t; i < 128 * 16; i += TPB)
        w1s[(i >> 4) * W1S + (i & 15)] = W1[i];
    __syncthreads();
    int g = t >> 2, q = t & 3;
    int n = id * 64 + g;
    int nc = min(n, N - 1);
    const float4* xr = (const float4*)(x + (size_t)nc * 128);
    float4 xv[8];
#pragma unroll
    for (int i = 0; i < 8; ++i) xv[i] = xr[i * 4 + q];   // 8 loads in flight
    float acc[16];
#pragma unroll
    for (int k = 0; k < 16; ++k) acc[k] = 0.f;
#pragma unroll
    for (int i = 0; i < 8; ++i) {
        float xj[4] = {xv[i].x, xv[i].y, xv[i].z, xv[i].w};
#pragma unroll
        for (int j = 0; j < 4; ++j) {
            int k = i * 16 + q * 4 + j;
            const float4* w4 = (const float4*)&w1s[k * W1S];
            float4 wa = w4[0], wb = w4[1], wc = w4[2], wd = w4[3];
            float xc = xj[j];
            acc[0]  = fmaf(xc, wa.x, acc[0]);  acc[1]  = fmaf(xc, wa.y, acc[1]);
            acc[2]  = fmaf(xc, wa.z, acc[2]);  acc[3]  = fmaf(xc, wa.w, acc[3]);
            acc[4]  = fmaf(xc, wb.x, acc[4]);  acc[5]  = fmaf(xc, wb.y, acc[5]);
            acc[6]  = fmaf(xc, wb.z, acc[6]);  acc[7]  = fmaf(xc, wb.w, acc[7]);
            acc[8]  = fmaf(xc, wc.x, acc[8]);  acc[9]  = fmaf(xc, wc.y, acc[9]);
            acc[10] = fmaf(xc, wc.z, acc[10]); acc[11] = fmaf(xc, wc.w, acc[11]);
            acc[12] = fmaf(xc, wd.x, acc[12]); acc[13] = fmaf(xc, wd.y, acc[13]);
            acc[14] = fmaf(xc, wd.z, acc[14]); acc[15] = fmaf(xc, wd.w, acc[15]);
        }
    }
    // butterfly-reduce acc across the 4 K-split lanes
#pragma unroll
    for (int d = 1; d < 4; d <<= 1) {
#pragma unroll
        for (int k = 0; k < 16; ++k) acc[k] += __shfl_xor(acc[k], d, 4);
    }
    if (n < N) {                             // lane q stores feats 4q..4q+3
        unsigned int u0 = (unsigned int)f2bf(acc[4 * q]) |
                          ((unsigned int)f2bf(acc[4 * q + 1]) << 16);
        unsigned int u1 = (unsigned int)f2bf(acc[4 * q + 2]) |
                          ((unsigned int)f2bf(acc[4 * q + 3]) << 16);
        *(uint2*)&h1b[(size_t)n * 16 + 4 * q] = make_uint2(u0, u1);
    }
}

// S2: one block per 512-node bucket: counting sort, emit csr/offs/dinv,
// h1p = bf16(dinv * h1b).
__global__ __launch_bounds__(TPB) void sort_kernel(
        const int* __restrict__ bucketed,
        const int* __restrict__ counts, const int* __restrict__ bsum,
        int E, int nblk, int nbuck,
        int* __restrict__ csr, int* __restrict__ offs, float* __restrict__ dinv,
        const unsigned short* __restrict__ h1b, unsigned short* __restrict__ h1p, int N) {
    __shared__ int lhist[NPB];
    __shared__ int part[TPB];
    __shared__ float sdinv[NPB];
    int bk = blockIdx.x, t = threadIdx.x;
    int n0 = bk << BK_SHIFT;
    int n1 = min(n0 + NPB, N);
    int e0 = cbase_at(counts, bsum, bk * nblk);
    int e1 = (bk + 1 < nbuck) ? cbase_at(counts, bsum, (bk + 1) * nblk) : E;

    lhist[t] = 0; lhist[t + TPB] = 0;
    __syncthreads();
    for (int i = e0 + t; i < e1; i += TPB)
        atomicAdd(&lhist[bucketed[i] >> 18], 1);               // LDS atomic
    __syncthreads();

    int base = t * 2;
    int c0 = lhist[base], c1 = lhist[base + 1];
    int s = c0 + c1;
    part[t] = s;
    __syncthreads();
    for (int off = 1; off < TPB; off <<= 1) {
        int v = (t >= off) ? part[t - off] : 0;
        __syncthreads();
        part[t] += v;
        __syncthreads();
    }
    int o0 = e0 + part[t] - s;
    int o1 = o0 + c0;
    lhist[base] = o0; lhist[base + 1] = o1;
    sdinv[base]     = rsqrtf((float)c0 + 1.0f);
    sdinv[base + 1] = rsqrtf((float)c1 + 1.0f);
    int n = n0 + base;
    if (n + 0 < N) { offs[n + 0] = o0; dinv[n + 0] = sdinv[base]; }
    if (n + 1 < N) { offs[n + 1] = o1; dinv[n + 1] = sdinv[base + 1]; }
    __syncthreads();

    for (int i = e0 + t; i < e1; i += TPB) {
        int v = bucketed[i];
        int pos = atomicAdd(&lhist[v >> 18], 1);               // LDS atomic
        csr[pos] = v & 0x3FFFF;
    }
    int nq = (n1 - n0) * 4;                  // one quad (4 feats) per i
    for (int i = t; i < nq; i += TPB) {
        float dv = sdinv[i >> 2];
        uint2 u = ((const uint2*)h1b)[(size_t)n0 * 4 + i];
        float f0 = bf2f((unsigned short)(u.x & 0xffff));
        float f1 = bf2f((unsigned short)(u.x >> 16));
        float f2 = bf2f((unsigned short)(u.y & 0xffff));
        float f3 = bf2f((unsigned short)(u.y >> 16));
        ((ushort4*)h1p)[(size_t)n0 * 4 + i] =
            make_ushort4(f2bf(f0 * dv), f2bf(f1 * dv), f2bf(f2 * dv), f2bf(f3 * dv));
    }
    if (bk == 0 && t == 0) offs[N] = E;
}

// gather1: 16 lanes/node, uint4 gathers: lane l -> edge slot (l>>1), half-row
// (l&1).  Per 16-edge csr window: 2 gather instrs (16 lanes x 16B) cover
// 16 edges x full row.  8-lane tree reduce; lanes 0/1 finalize 8 feats each.
// h2p[c] = bf16( dinv[c]*relu( dinv[c]*(sum h1p[src] + h1p[c]) + b1 ) )
__global__ __launch_bounds__(TPB) void gather1_kernel(const int* __restrict__ csr,
                                                      const int* __restrict__ offs,
                                                      const unsigned short* __restrict__ h1p,
                                                      const float* __restrict__ dinv,
                                                      const float* __restrict__ b1,
                                                      unsigned short* __restrict__ h2p, int N) {
    int t = threadIdx.x;
    int c = blockIdx.x * 16 + (t >> 4);
    int l = t & 15;
    int half = l & 1;                        // which 8-feature half-row
    int sub  = l >> 1;                       // edge slot 0..7
    if (c >= N) return;
    int p0 = offs[c], p1 = offs[c + 1];
    float a[8];
#pragma unroll
    for (int k = 0; k < 8; ++k) a[k] = 0.f;
    for (int p = p0; p < p1; p += 16) {
        int s16 = csr[min(p + l, p1 - 1)];
#pragma unroll
        for (int h = 0; h < 2; ++h) {
            int e = 8 * h + sub;
            int src = __shfl(s16, e, 16);
            unsigned int m = ((p + e) < p1) ? 0xffffffffu : 0u;
            uint4 v = *(const uint4*)&h1p[(size_t)src * 16 + 8 * half];
            bfacc8(v, m, a);
        }
    }
#pragma unroll
    for (int d = 2; d < 16; d <<= 1) {
#pragma unroll
        for (int k = 0; k < 8; ++k) a[k] += __shfl_xor(a[k], d, 16);
    }
    if (l < 2) {                             // l==half here
        float dc = dinv[c];
        uint4 sv = *(const uint4*)&h1p[(size_t)c * 16 + 8 * l];
        float sf[8];
        bfunp8(sv, sf);
        unsigned int uo[4];
#pragma unroll
        for (int q = 0; q < 4; ++q) {
            float r0 = fmaf(dc, a[2 * q] + sf[2 * q], b1[8 * l + 2 * q]);
            float r1 = fmaf(dc, a[2 * q + 1] + sf[2 * q + 1], b1[8 * l + 2 * q + 1]);
            r0 = dc * fmaxf(r0, 0.f);
            r1 = dc * fmaxf(r1, 0.f);
            uo[q] = (unsigned int)f2bf(r0) | ((unsigned int)f2bf(r1) << 16);
        }
        *(uint4*)&h2p[(size_t)c * 16 + 8 * l] = make_uint4(uo[0], uo[1], uo[2], uo[3]);
    }
}

// gather2f: fused gather2 + W2 matmul + sorted-batch pooling.  Block = 64 nodes.
// Phase 1: 16 groups x 16 lanes gather a2 rows (4 nodes/group, uint4 gathers
// as in gather1) into LDS asT.
// Phase 2: wave w: 64 lanes = output dims, 16 nodes from asT, W2 slice in regs,
//          run-accumulate; uniform-batch blocks pool in LDS, flush 64 atomics.
__global__ __launch_bounds__(TPB) void gather2f_kernel(
        const int* __restrict__ csr, const int* __restrict__ offs,
        const unsigned short* __restrict__ h2p, const float* __restrict__ dinv,
        const float* __restrict__ W2, const float* __restrict__ b2,
        const int* __restrict__ batch, float* __restrict__ out, int N) {
    __shared__ float w2s[16 * 64];
    __shared__ float asT[64 * 17];
    __shared__ float pool[64];
    int t = threadIdx.x;
    for (int i = t; i < 16 * 64; i += TPB) w2s[i] = W2[i];
    if (t < 64) pool[t] = 0.f;

    int n0 = blockIdx.x * 64;
    int nLast = min(n0 + 63, N - 1);
    int g0 = batch[n0];
    bool uniform = (batch[nLast] == g0);     // batch sorted

    // phase 1: gather (4 nodes per 16-lane group, uint4 loads)
    int grp = t >> 4, l = t & 15;
    int half = l & 1, sub = l >> 1;
#pragma unroll 1
    for (int it = 0; it < 4; ++it) {
        int m = grp * 4 + it;
        int c = n0 + m;
        if (c < N) {
            int p0 = offs[c], p1 = offs[c + 1];
            float a[8];
#pragma unroll
            for (int k = 0; k < 8; ++k) a[k] = 0.f;
            for (int p = p0; p < p1; p += 16) {
                int s16 = csr[min(p + l, p1 - 1)];
#pragma unroll
                for (int h = 0; h < 2; ++h) {
                    int e = 8 * h + sub;
                    int src = __shfl(s16, e, 16);
                    unsigned int mm = ((p + e) < p1) ? 0xffffffffu : 0u;
                    uint4 v = *(const uint4*)&h2p[(size_t)src * 16 + 8 * half];
                    bfacc8(v, mm, a);
                }
            }
#pragma unroll
            for (int d = 2; d < 16; d <<= 1) {
#pragma unroll
                for (int k = 0; k < 8; ++k) a[k] += __shfl_xor(a[k], d, 16);
            }
            if (l < 2) {
                float dc = dinv[c];
                uint4 sv = *(const uint4*)&h2p[(size_t)c * 16 + 8 * l];
                float sf[8];
                bfunp8(sv, sf);
#pragma unroll
                for (int k = 0; k < 8; ++k)
                    asT[m * 17 + 8 * l + k] = dc * (a[k] + sf[k]);
            }
        }
    }
    __syncthreads();

    // phase 2: wave w covers nodes n0+16w .. n0+16w+15
    int wave = t >> 6, j = t & 63;
    float w2reg[16];
#pragma unroll
    for (int kx = 0; kx < 16; ++kx) w2reg[kx] = w2s[kx * 64 + j];
    float b2j = b2[j];
    float val = 0.f;
    int g_cur = -1;
#pragma unroll 1
    for (int mi = 0; mi < 16; ++mi) {
        int m = wave * 16 + mi;
        int c = n0 + m;
        if (c >= N) break;
        const float* ar = &asT[m * 17];
        float y = b2j;
#pragma unroll
        for (int kx = 0; kx < 16; ++kx) y = fmaf(ar[kx], w2reg[kx], y);
        if (uniform) {
            val += y;
        } else {
            int g = batch[c];
            if (g != g_cur) {
                if (g_cur >= 0) atomicAdd(&out[(size_t)g_cur * 64 + j], val);
                val = 0.f;
                g_cur = g;
            }
            val += y;
        }
    }
    if (uniform) {
        atomicAdd(&pool[j], val);            // LDS, 4-way per address
        __syncthreads();
        if (t < 64) atomicAdd(&out[(size_t)g0 * 64 + t], pool[t]);
    } else {
        if (g_cur >= 0) atomicAdd(&out[(size_t)g_cur * 64 + j], val);
    }
}

static inline size_t align64(size_t v) { return (v + 63) & ~(size_t)63; }

extern "C" void kernel_launch(void* const* d_in, const int* in_sizes, int n_in,
                              void* d_out, int out_size, void* d_ws, size_t ws_size,
                              hipStream_t stream) {
    const float* x     = (const float*)d_in[0];
    const int*   ei    = (const int*)d_in[1];
    const int*   batch = (const int*)d_in[2];
    const float* W1    = (const float*)d_in[3];
    const float* b1    = (const float*)d_in[4];
    const float* W2    = (const float*)d_in[5];
    const float* b2    = (const float*)d_in[6];

    const int N = in_sizes[0] / 128;
    const int E = in_sizes[1] / 2;
    const int* row = ei;        // edge_index[0]
    const int* col = ei + E;    // edge_index[1]

    const int NBLK  = (E + CHUNK - 1) / CHUNK;       // 782
    const int NBUCK = (N + NPB - 1) / NPB;           // 391 (<=512)
    const int L     = NBUCK * NBLK;                  // 305762
    const int NBS   = (L + TPB - 1) / TPB;           // 1195 (<=2048 for scan2)
    const int NBG   = (N + 63) / 64;                 // 3125 gemm blocks (64 nodes each)

    char* p = (char*)d_ws;
    int*            counts   = (int*)p;            p += align64((size_t)L * 4);
    int*            bsum     = (int*)p;            p += align64(2048 * 4);
    int*            bucketed = (int*)p;            p += align64((size_t)E * 4);
    int*            csr      = (int*)p;            p += align64((size_t)E * 4);
    int*            offs     = (int*)p;            p += align64((size_t)(N + 1) * 4);
    float*          dinv     = (float*)p;          p += align64((size_t)N * 4);
    unsigned short* h1b      = (unsigned short*)p; p += align64((size_t)N * 16 * 2);
    unsigned short* h1p      = (unsigned short*)p; p += align64((size_t)N * 16 * 2);
    unsigned short* h2p      = (unsigned short*)p; p += align64((size_t)N * 16 * 2);
    float*          out      = (float*)d_out;

    hipMemsetAsync(out, 0, (size_t)out_size * sizeof(float), stream);

    hist_kernel<<<NBLK, TPB, 0, stream>>>(col, counts, E, NBLK, NBUCK);
    scan1_kernel<<<NBS, TPB, 0, stream>>>(counts, counts, bsum, L);
    scan2_kernel<<<1, 1024, 0, stream>>>(bsum, NBS);
    s1c_gemm_kernel<<<NBLK + NBG, TPB, 0, stream>>>(row, col, counts, bsum,
                                                    E, NBLK, NBUCK,
                                                    bucketed, x, W1, h1b, N, NBG);
    sort_kernel<<<NBUCK, TPB, 0, stream>>>(bucketed, counts, bsum, E, NBLK, NBUCK,
                                           csr, offs, dinv, h1b, h1p, N);
    gather1_kernel<<<(N + 15) / 16, TPB, 0, stream>>>(csr, offs, h1p, dinv, b1, h2p, N);
    gather2f_kernel<<<(N + 63) / 64, TPB, 0, stream>>>(csr, offs, h2p, dinv,
                                                       W2, b2, batch, out, N);
}